// Round 1
// baseline (33.056 us; speedup 1.0000x reference)
//
#include <hip/hip_runtime.h>
#include <math.h>

#define NQ   12
#define DIM  4096
#define KOUT 10
#define BATCH 4096

// XOR-swizzle on linear LDS float index: XOR bits 6-8 (row) into bits 2-4
// (16B-granule slot). Makes row-contiguous b128 reads (lane-stride 64 floats)
// AND strided-64 b32 transpose writes bank-conflict-free. Involution.
__device__ __forceinline__ int swzAddr(int lin) {
    return lin ^ (((lin >> 6) & 7) << 2);
}

// 6 butterfly layers on lane-local 64-element state.
// local bit k <-> theta index BASE+k (broadcast from lane BASE+k).
template<int BASE>
__device__ __forceinline__ void bfly6(float r[64], float myc, float mys) {
#pragma unroll
    for (int k = 0; k < 6; ++k) {
        float c = __shfl(myc, BASE + k, 64);
        float s = __shfl(mys, BASE + k, 64);
#pragma unroll
        for (int m = 0; m < 32; ++m) {
            int i0 = ((m >> k) << (k + 1)) | (m & ((1 << k) - 1));
            int i1 = i0 | (1 << k);
            float a = r[i0], bb = r[i1];
            r[i0] = c * a - s * bb;
            r[i1] = s * a + c * bb;
        }
    }
}

// read 64 floats: r[j] = lds_logical[l*64 + j], via swizzled b128 reads
__device__ __forceinline__ void ldsRead64(const float* lds, int l, float r[64]) {
#pragma unroll
    for (int e4 = 0; e4 < 16; ++e4) {
        int lin = l * 64 + e4 * 4;
        const float4 w = *reinterpret_cast<const float4*>(&lds[swzAddr(lin)]);
        r[e4 * 4 + 0] = w.x; r[e4 * 4 + 1] = w.y;
        r[e4 * 4 + 2] = w.z; r[e4 * 4 + 3] = w.w;
    }
}

// transposed write: element held at local j goes to linear j*64 + l
// (conflict-free b32: lanes consecutive within a 64-float run, XOR-perturbed)
__device__ __forceinline__ void ldsWriteT(float* lds, int l, const float r[64]) {
#pragma unroll
    for (int j = 0; j < 64; ++j) {
        int T = j * 64 + l;
        lds[swzAddr(T)] = r[j];
    }
}

__global__ __launch_bounds__(64) void vqc_kernel(
        const float* __restrict__ x,
        const float* __restrict__ theta,
        float* __restrict__ out)
{
    __shared__ __align__(16) float lds[DIM];
    const int l = threadIdx.x;   // lane 0..63; one wave per block, one batch row per block
    const int b = blockIdx.x;

    // per-lane theta: lane i<24 holds cos/sin(theta[i]/2); broadcast later via readlane
    float th  = theta[l < 24 ? l : 0];
    float myc = cosf(0.5f * th);
    float mys = sinf(0.5f * th);

    // ---- stage x row into LDS (identity layout, swizzled), coalesced float4 ----
    const float4* x4 = reinterpret_cast<const float4*>(x + (size_t)b * DIM);
#pragma unroll
    for (int it = 0; it < 16; ++it) {
        int G = it * 64 + l;                 // logical 16B granule index
        float4 w = x4[G];
        int PG = G ^ ((G >> 4) & 7);         // = swzAddr granule form
        *reinterpret_cast<float4*>(&lds[PG * 4]) = w;
    }

    float r[64];

    // ---- pass 1: qubits 0-5, layer 1 (thread l holds d = l*64 + j) ----
    ldsRead64(lds, l, r);
    bfly6<0>(r, myc, mys);
    ldsWriteT(lds, l, r);                    // -> transposed layout

    // ---- pass 2: qubits 6-11 (thread l holds d = (j<<6) | l) ----
    ldsRead64(lds, l, r);                    // r[j] = state[(j<<6)|l]
    bfly6<6>(r, myc, mys);                   // layer-1 RY on qubits 6..11

    // CZ diagonal: pairs (i,i+1) i=0..10 and (0,11); d = (e<<6)|l
    {
        int f  = __popc(l & (l >> 1) & 0x1F) & 1;  // pairs among l-bits (qubits 0-5)
        int l5 = (l >> 5) & 1, l0 = l & 1;
        float sg0 = f              ? -1.f : 1.f;
        float sg1 = (f ^ l5)       ? -1.f : 1.f;
        float sg2 = (f ^ l0)       ? -1.f : 1.f;
        float sg3 = (f ^ l5 ^ l0)  ? -1.f : 1.f;
#pragma unroll
        for (int e = 0; e < 64; ++e) {
            const int Ce  = __popc(e & (e >> 1) & 0x1F) & 1;      // pairs among e-bits (qubits 6-11)
            const int sel = (e & 1) | (((e >> 5) & 1) << 1);      // (5,6) needs l5; (0,11) needs l0
            float sgn;
            if      (sel == 0) sgn = sg0;
            else if (sel == 1) sgn = sg1;
            else if (sel == 2) sgn = sg2;
            else               sgn = sg3;
            r[e] *= (Ce ? -sgn : sgn);
        }
    }

    bfly6<18>(r, myc, mys);                  // layer-2 RY on qubits 6..11 (theta[12+6+k])
    ldsWriteT(lds, l, r);                    // transpose back -> identity layout

    // ---- pass 3: qubits 0-5, layer 2 + measurement (d = l*64 + j) ----
    ldsRead64(lds, l, r);
    bfly6<12>(r, myc, mys);

    // probs p = r^2 ; out_k = sum_d bit_k(d) * p.  bits 0-5 = j, bits 6-9 = l&15.
    float psum = 0.f;
#pragma unroll
    for (int j = 0; j < 64; ++j) psum = fmaf(r[j], r[j], psum);

    float v[10];
#pragma unroll
    for (int k = 0; k < 6; ++k) {
        float mk = 0.f;
#pragma unroll
        for (int j = 0; j < 64; ++j)
            if (j & (1 << k)) mk = fmaf(r[j], r[j], mk);
        v[k] = mk;
    }
    v[6] = (l & 1) ? psum : 0.f;
    v[7] = (l & 2) ? psum : 0.f;
    v[8] = (l & 4) ? psum : 0.f;
    v[9] = (l & 8) ? psum : 0.f;

    // wave-level butterfly reduction (all lanes end with the total)
#pragma unroll
    for (int k = 0; k < 10; ++k) {
        float t = v[k];
#pragma unroll
        for (int off = 32; off >= 1; off >>= 1)
            t += __shfl_xor(t, off, 64);
        v[k] = t;
    }

    if (l == 0) {
#pragma unroll
        for (int k = 0; k < KOUT; ++k) out[b * KOUT + k] = v[k];
    }
}

extern "C" void kernel_launch(void* const* d_in, const int* in_sizes, int n_in,
                              void* d_out, int out_size, void* d_ws, size_t ws_size,
                              hipStream_t stream) {
    const float* x     = (const float*)d_in[0];
    const float* theta = (const float*)d_in[1];
    float* out         = (float*)d_out;
    vqc_kernel<<<BATCH, 64, 0, stream>>>(x, theta, out);
}